// Round 12
// baseline (137.178 us; speedup 1.0000x reference)
//
#include <hip/hip_runtime.h>

// LSTM: B=1024, T=128, H=256, C=10.
// Round 12: r10's validated compute (EXTRACT scheme, absmax-passing 5 rounds)
// + NEW sync: no per-step __syncthreads. Per-wave LDS flags (release/acquire,
// workgroup scope = pure ds ops) + TRIPLE-buffered h. Wave w owns units
// [16w,16w+16); consumers spin per K-chunk (chunk kk <- flags 4kk..4kk+3, static
// wa indexing) so waves de-lockstep and epilogue VALU of one wave hides under
// another's MFMA stream. WAR-safe: write of h(t+1) happens after seeing all
// flg>=t => all waves completed step t-1 => all reads of h(t-2) (the buffer
// being overwritten) are done. Deadlock-free (monotone flags).

#define TSTEPS  128
#define HDIM    256
#define NCLS    10
#define BB      4
#define NBLOCKS 256
#define NTHR    1024

#define XSTR    132                 // floats per x row
#define HSTR    320                 // bytes per h row
#define HBUF    (BB * HSTR)         // 1280 B per buffer
#define PSTR    260

typedef char  i8x16 __attribute__((ext_vector_type(16)));
typedef int   i32x4 __attribute__((ext_vector_type(4)));

#define L2E     1.4426950408889634f
#define MGC     (-2.0f * L2E)
#define SMG     (-2.0f * L2E / 16129.0f)   // acc scale, tanh gate (1/(127*127))
#define SMS     (-1.0f * L2E / 16129.0f)   // acc scale, sigmoid gates

static __device__ __forceinline__ float rcpf(float x) { return __builtin_amdgcn_rcpf(x); }
static __device__ __forceinline__ float exp2f_fast(float x) { return __builtin_amdgcn_exp2f(x); }

#define MFMA_I8(ACC, A, B) \
    asm("v_mfma_i32_16x16x64_i8 %0, %1, %2, %0" : "+v"(ACC) : "v"(A), "a"(B))

// select element j=lq from this lane's 4 acc regs (3 cndmask) — r10-validated
#define EXTRACT(V) (s1 ? (s0 ? (V)[3] : (V)[2]) : (s0 ? (V)[1] : (V)[0]))

// gates from 4 pre-scaled logits; updates c, returns h
static __device__ __forceinline__ float gate_h(float zs0, float zs1, float zs2,
                                               float zs3, float& c)
{
    const float eg = exp2f_fast(zs0), ei = exp2f_fast(zs1);
    const float ef = exp2f_fast(zs2), eo = exp2f_fast(zs3);
    const float rg = rcpf(1.0f + eg), ri = rcpf(1.0f + ei);
    const float rf = rcpf(1.0f + ef), ro = rcpf(1.0f + eo);
    const float gg = __builtin_fmaf(2.0f, rg, -1.0f);          // tanh
    const float cc = __builtin_fmaf(c, rf, gg * ri);
    c = cc;
    const float et = exp2f_fast(cc * MGC);
    const float rt = rcpf(1.0f + et);
    const float tc = __builtin_fmaf(2.0f, rt, -1.0f);
    return tc * ro;
}

// ---------------- pre-kernel: quantize + transpose Wh to int8 [gate][unit][k] ----
__global__ __launch_bounds__(64)
void pack_w(const float* __restrict__ wg, const float* __restrict__ wi,
            const float* __restrict__ wf, const float* __restrict__ wo,
            signed char* __restrict__ wq8)
{
    const int b = blockIdx.x;            // 0..1023
    const int q = b >> 8;                // gate
    const int u = b & 255;               // unit (column)
    const float* wp = (q == 0) ? wg : (q == 1) ? wi : (q == 2) ? wf : wo;
    const int t  = threadIdx.x;          // 0..63
    const int k0 = t * 4;
    unsigned int pk = 0;
#pragma unroll
    for (int i = 0; i < 4; ++i) {
        const float v = wp[(k0 + i) * HDIM + u];
        int qv = __float2int_rn(v * 127.0f);
        qv = (qv > 127) ? 127 : ((qv < -127) ? -127 : qv);
        pk |= ((unsigned int)qv & 255u) << (8 * i);
    }
    *(unsigned int*)(wq8 + ((size_t)(q * 256 + u) * 256 + k0)) = pk;
}

// ---------------- main persistent kernel ----------------------------------------
__global__ __launch_bounds__(NTHR, 4)
void lstm_full(const float* __restrict__ x,
               const float* __restrict__ w_gx, const float* __restrict__ w_ix,
               const float* __restrict__ w_fx, const float* __restrict__ w_ox,
               const float* __restrict__ b_g,  const float* __restrict__ b_i,
               const float* __restrict__ b_f,  const float* __restrict__ b_o,
               const float* __restrict__ w_ph, const float* __restrict__ b_p,
               const signed char* __restrict__ wq8,
               float* __restrict__ out)
{
    const int g    = blockIdx.x;         // 0..255, batch rows [g*4, g*4+4)
    const int tid  = threadIdx.x;
    const int w    = tid >> 6;           // wave 0..15
    const int lane = tid & 63;
    const int l16  = lane & 15;
    const int lq   = lane >> 4;          // 0..3  == this lane's batch row

    __shared__ float        x_lds[BB * XSTR];           // 2.1 KB
    __shared__ signed char  h_q[3 * HBUF];              // 3.75 KB (triple buffer)
    __shared__ float        proj[BB * PSTR];            // 4.2 KB
    __shared__ int          flg[16];                    // per-wave publish flags

    {   // x tile: 4 rows x 128 steps
        const float* xs = x + (size_t)g * BB * TSTEPS;
        for (int i = tid; i < BB * TSTEPS; i += NTHR)
            x_lds[(i >> 7) * XSTR + (i & 127)] = xs[i];
    }
    if (tid < 16) flg[tid] = 0;

    // ---- int8 B-fragments, pinned in AGPRs (volatile def: no sink/remat) --------
    // wave w owns units u = w*16 + l16 (ONE unit per lane), all 4 gates.
    const int u = w * 16 + l16;
    i32x4 wa[4][4];
#pragma unroll
    for (int q = 0; q < 4; ++q)
#pragma unroll
        for (int kk = 0; kk < 4; ++kk) {
            const signed char* p = wq8 + ((size_t)(q * 256 + u) * 256)
                                       + kk * 64 + lq * 16;
            i32x4 v = __builtin_bit_cast(i32x4, *(const i8x16*)p);
            asm volatile("" : "+a"(v));
            wa[q][kk] = v;
        }

    const float* const wxp[4] = {w_gx, w_ix, w_fx, w_ox};
    const float* const bbp[4] = {b_g, b_i, b_f, b_o};
    float wxm[4], bm[4];
#pragma unroll
    for (int q = 0; q < 4; ++q) {
        const float m = (q == 0) ? MGC : (-L2E);
        wxm[q] = wxp[q][u] * m;
        bm[q]  = bbp[q][u] * m;
    }

    float c = 0.f;                       // cell state: lane owns (row=lq, unit u)
    const bool s0 = (lq & 1) != 0;
    const bool s1 = (lq & 2) != 0;
    const int  woff = lq * HSTR + u;     // h write offset (1 byte per lane)
    const int  fi   = lane & 3;          // flag sub-index for chunk spins

    __syncthreads();                     // x_lds + flg init visible to all

    // ---- t = 0 peel: h(1) = f(x0, h0=0) -> buffer 1, flag 1 ---------------------
    {
        const float xv = x_lds[lq * XSTR + 0];
        const float hh = gate_h(__builtin_fmaf(xv, wxm[0], bm[0]),
                                __builtin_fmaf(xv, wxm[1], bm[1]),
                                __builtin_fmaf(xv, wxm[2], bm[2]),
                                __builtin_fmaf(xv, wxm[3], bm[3]), c);
        h_q[HBUF + woff] = (signed char)__float2int_rn(hh * 127.0f);
        if (lane == 0)
            __hip_atomic_store(&flg[w], 1, __ATOMIC_RELEASE,
                               __HIP_MEMORY_SCOPE_WORKGROUP);
    }

    // triple-buffer byte offsets: read h(t), write h(t+1), spare holds h(t-1)
    int oR = HBUF, oW = 2 * HBUF, oS = 0;

    // ---- main loop: t = 1 .. 127 (no block barrier) ------------------------------
    for (int t = 1; t < TSTEPS; ++t) {
        const signed char* hs = &h_q[oR + (l16 & 3) * HSTR];
        i32x4 a[4] = {{0,0,0,0},{0,0,0,0},{0,0,0,0},{0,0,0,0}};

#pragma unroll
        for (int kk = 0; kk < 4; ++kk) {
            // chunk kk (h units 64kk..64kk+63) produced by waves 4kk..4kk+3
            while (__hip_atomic_load(&flg[4 * kk + fi], __ATOMIC_ACQUIRE,
                                     __HIP_MEMORY_SCOPE_WORKGROUP) < t) { }
            const i32x4 ah = *(const i32x4*)(hs + kk * 64 + lq * 16);
#pragma unroll
            for (int q = 0; q < 4; ++q)
                MFMA_I8(a[q], ah, wa[q][kk]);
        }

        // epilogue: ONE output per lane (row=lq, unit u); acc j=lq via selects
        const float xv = x_lds[lq * XSTR + t];
        const float zs0 = __builtin_fmaf((float)EXTRACT(a[0]), SMG,
                          __builtin_fmaf(xv, wxm[0], bm[0]));
        const float zs1 = __builtin_fmaf((float)EXTRACT(a[1]), SMS,
                          __builtin_fmaf(xv, wxm[1], bm[1]));
        const float zs2 = __builtin_fmaf((float)EXTRACT(a[2]), SMS,
                          __builtin_fmaf(xv, wxm[2], bm[2]));
        const float zs3 = __builtin_fmaf((float)EXTRACT(a[3]), SMS,
                          __builtin_fmaf(xv, wxm[3], bm[3]));
        const float hh = gate_h(zs0, zs1, zs2, zs3, c);

        h_q[oW + woff] = (signed char)__float2int_rn(hh * 127.0f);
        if (t == TSTEPS - 1) proj[lq * PSTR + u] = hh;

        // publish: release orders the h ds_write (lgkmcnt drain) before the flag
        if (lane == 0)
            __hip_atomic_store(&flg[w], t + 1, __ATOMIC_RELEASE,
                               __HIP_MEMORY_SCOPE_WORKGROUP);

        const int tmp = oS; oS = oR; oR = oW; oW = tmp;   // rotate buffers
    }

    __syncthreads();                     // all proj writes done

    // ---- final projection: out[g*4 + r][cls], 4x10 -------------------------------
    if (tid < BB * NCLS) {
        const int r = tid / NCLS, cls = tid - r * NCLS;
        float a = b_p[cls];
#pragma unroll 8
        for (int uu = 0; uu < HDIM; ++uu)
            a = __builtin_fmaf(proj[r * PSTR + uu], w_ph[uu * NCLS + cls], a);
        out[(size_t)(g * BB + r) * NCLS + cls] = a;
    }
}

extern "C" void kernel_launch(void* const* d_in, const int* in_sizes, int n_in,
                              void* d_out, int out_size, void* d_ws, size_t ws_size,
                              hipStream_t stream)
{
    const float* x    = (const float*)d_in[0];
    const float* w_gx = (const float*)d_in[1];
    const float* w_ix = (const float*)d_in[2];
    const float* w_fx = (const float*)d_in[3];
    const float* w_ox = (const float*)d_in[4];
    const float* w_gh = (const float*)d_in[5];
    const float* w_ih = (const float*)d_in[6];
    const float* w_fh = (const float*)d_in[7];
    const float* w_oh = (const float*)d_in[8];
    const float* b_g  = (const float*)d_in[9];
    const float* b_i  = (const float*)d_in[10];
    const float* b_f  = (const float*)d_in[11];
    const float* b_o  = (const float*)d_in[12];
    const float* w_ph = (const float*)d_in[13];
    const float* b_p  = (const float*)d_in[14];

    signed char* wq8 = (signed char*)d_ws;   // 4*256*256 = 256 KB

    hipLaunchKernelGGL(pack_w, dim3(1024), dim3(64), 0, stream,
                       w_gh, w_ih, w_fh, w_oh, wq8);

    hipLaunchKernelGGL(lstm_full, dim3(NBLOCKS), dim3(NTHR), 0, stream,
                       x, w_gx, w_ix, w_fx, w_ox,
                       b_g, b_i, b_f, b_o, w_ph, b_p,
                       wq8, (float*)d_out);
}

// Round 13
// 128.487 us; speedup vs baseline: 1.0676x; 1.0676x over previous
//
#include <hip/hip_runtime.h>

// LSTM: B=1024, T=128, H=256, C=10.
// Round 13: r10 compute (EXTRACT, validated) + r12 sync (flags + triple buffer,
// validated) + NEW: rotated chunk consumption. Wave w consumes K-chunks in order
// j0, j0+1, j0+2, j0+3 (mod 4) with j0 = w>>2 (its OWN chunk first - producers are
// its phase-siblings). Wave groups de-phase so epilogue VALU of group j overlaps
// group j+1's MFMA stream (r10 counters: VALU 1434 + MFMA 1050 cyc ran ~serially).
// wa[] stays statically indexed by PERMUTING the weight load (chunk (j0+n)&3 ->
// slot n). First chunk uses zero-C MFMA (no 16x v_mov acc init).

#define TSTEPS  128
#define HDIM    256
#define NCLS    10
#define BB      4
#define NBLOCKS 256
#define NTHR    1024

#define XSTR    132                 // floats per x row
#define HSTR    320                 // bytes per h row
#define HBUF    (BB * HSTR)         // 1280 B per buffer
#define PSTR    260

typedef char  i8x16 __attribute__((ext_vector_type(16)));
typedef int   i32x4 __attribute__((ext_vector_type(4)));

#define L2E     1.4426950408889634f
#define MGC     (-2.0f * L2E)
#define SMG     (-2.0f * L2E / 16129.0f)   // acc scale, tanh gate (1/(127*127))
#define SMS     (-1.0f * L2E / 16129.0f)   // acc scale, sigmoid gates

static __device__ __forceinline__ float rcpf(float x) { return __builtin_amdgcn_rcpf(x); }
static __device__ __forceinline__ float exp2f_fast(float x) { return __builtin_amdgcn_exp2f(x); }

#define MFMA_I8(ACC, A, B) \
    asm("v_mfma_i32_16x16x64_i8 %0, %1, %2, %0" : "+v"(ACC) : "v"(A), "a"(B))
#define MFMA_I8_Z(ACC, A, B, Z) \
    asm("v_mfma_i32_16x16x64_i8 %0, %1, %2, %3" : "=v"(ACC) : "v"(A), "a"(B), "v"(Z))

// select element j=lq from this lane's 4 acc regs (3 cndmask) — validated r10/r12
#define EXTRACT(V) (s1 ? (s0 ? (V)[3] : (V)[2]) : (s0 ? (V)[1] : (V)[0]))

// gates from 4 pre-scaled logits; updates c, returns h
static __device__ __forceinline__ float gate_h(float zs0, float zs1, float zs2,
                                               float zs3, float& c)
{
    const float eg = exp2f_fast(zs0), ei = exp2f_fast(zs1);
    const float ef = exp2f_fast(zs2), eo = exp2f_fast(zs3);
    const float rg = rcpf(1.0f + eg), ri = rcpf(1.0f + ei);
    const float rf = rcpf(1.0f + ef), ro = rcpf(1.0f + eo);
    const float gg = __builtin_fmaf(2.0f, rg, -1.0f);          // tanh
    const float cc = __builtin_fmaf(c, rf, gg * ri);
    c = cc;
    const float et = exp2f_fast(cc * MGC);
    const float rt = rcpf(1.0f + et);
    const float tc = __builtin_fmaf(2.0f, rt, -1.0f);
    return tc * ro;
}

// ---------------- pre-kernel: quantize + transpose Wh to int8 [gate][unit][k] ----
__global__ __launch_bounds__(64)
void pack_w(const float* __restrict__ wg, const float* __restrict__ wi,
            const float* __restrict__ wf, const float* __restrict__ wo,
            signed char* __restrict__ wq8)
{
    const int b = blockIdx.x;            // 0..1023
    const int q = b >> 8;                // gate
    const int u = b & 255;               // unit (column)
    const float* wp = (q == 0) ? wg : (q == 1) ? wi : (q == 2) ? wf : wo;
    const int t  = threadIdx.x;          // 0..63
    const int k0 = t * 4;
    unsigned int pk = 0;
#pragma unroll
    for (int i = 0; i < 4; ++i) {
        const float v = wp[(k0 + i) * HDIM + u];
        int qv = __float2int_rn(v * 127.0f);
        qv = (qv > 127) ? 127 : ((qv < -127) ? -127 : qv);
        pk |= ((unsigned int)qv & 255u) << (8 * i);
    }
    *(unsigned int*)(wq8 + ((size_t)(q * 256 + u) * 256 + k0)) = pk;
}

// ---------------- main persistent kernel ----------------------------------------
__global__ __launch_bounds__(NTHR, 4)
void lstm_full(const float* __restrict__ x,
               const float* __restrict__ w_gx, const float* __restrict__ w_ix,
               const float* __restrict__ w_fx, const float* __restrict__ w_ox,
               const float* __restrict__ b_g,  const float* __restrict__ b_i,
               const float* __restrict__ b_f,  const float* __restrict__ b_o,
               const float* __restrict__ w_ph, const float* __restrict__ b_p,
               const signed char* __restrict__ wq8,
               float* __restrict__ out)
{
    const int g    = blockIdx.x;         // 0..255, batch rows [g*4, g*4+4)
    const int tid  = threadIdx.x;
    const int w    = tid >> 6;           // wave 0..15
    const int lane = tid & 63;
    const int l16  = lane & 15;
    const int lq   = lane >> 4;          // 0..3  == this lane's batch row

    __shared__ float        x_lds[BB * XSTR];           // 2.1 KB
    __shared__ signed char  h_q[3 * HBUF];              // 3.75 KB (triple buffer)
    __shared__ float        proj[BB * PSTR];            // 4.2 KB
    __shared__ int          flg[16];                    // per-wave publish flags

    {   // x tile: 4 rows x 128 steps
        const float* xs = x + (size_t)g * BB * TSTEPS;
        for (int i = tid; i < BB * TSTEPS; i += NTHR)
            x_lds[(i >> 7) * XSTR + (i & 127)] = xs[i];
    }
    if (tid < 16) flg[tid] = 0;

    // ---- int8 B-fragments, pinned in AGPRs; load PERMUTED by j0 -----------------
    // wave w owns units u = w*16 + l16 (chunk j0 = w>>2). Slot n holds chunk
    // (j0+n)&3 so the hot loop indexes wa statically while consuming chunks in
    // rotated order (own chunk first).
    const int u  = w * 16 + l16;
    const int j0 = w >> 2;
    i32x4 wa[4][4];
#pragma unroll
    for (int q = 0; q < 4; ++q)
#pragma unroll
        for (int n = 0; n < 4; ++n) {
            const int chunk = (j0 + n) & 3;
            const signed char* p = wq8 + ((size_t)(q * 256 + u) * 256)
                                       + chunk * 64 + lq * 16;
            i32x4 v = __builtin_bit_cast(i32x4, *(const i8x16*)p);
            asm volatile("" : "+a"(v));
            wa[q][n] = v;
        }

    const float* const wxp[4] = {w_gx, w_ix, w_fx, w_ox};
    const float* const bbp[4] = {b_g, b_i, b_f, b_o};
    float wxm[4], bm[4];
#pragma unroll
    for (int q = 0; q < 4; ++q) {
        const float m = (q == 0) ? MGC : (-L2E);
        wxm[q] = wxp[q][u] * m;
        bm[q]  = bbp[q][u] * m;
    }

    i32x4 zz = {0, 0, 0, 0};
    asm("" : "+v"(zz));                  // keep a live zero C-operand

    float c = 0.f;                       // cell state: lane owns (row=lq, unit u)
    const bool s0 = (lq & 1) != 0;
    const bool s1 = (lq & 2) != 0;
    const int  woff = lq * HSTR + u;     // h write offset (1 byte per lane)
    const int  fi   = lane & 3;          // flag sub-index for chunk spins

    __syncthreads();                     // x_lds + flg init visible to all

    // ---- t = 0 peel: h(1) = f(x0, h0=0) -> buffer 1, flag 1 ---------------------
    {
        const float xv = x_lds[lq * XSTR + 0];
        const float hh = gate_h(__builtin_fmaf(xv, wxm[0], bm[0]),
                                __builtin_fmaf(xv, wxm[1], bm[1]),
                                __builtin_fmaf(xv, wxm[2], bm[2]),
                                __builtin_fmaf(xv, wxm[3], bm[3]), c);
        h_q[HBUF + woff] = (signed char)__float2int_rn(hh * 127.0f);
        if (lane == 0)
            __hip_atomic_store(&flg[w], 1, __ATOMIC_RELEASE,
                               __HIP_MEMORY_SCOPE_WORKGROUP);
    }

    // triple-buffer byte offsets: read h(t), write h(t+1), spare holds h(t-1)
    int oR = HBUF, oW = 2 * HBUF, oS = 0;

    // ---- main loop: t = 1 .. 127 (no block barrier) ------------------------------
    for (int t = 1; t < TSTEPS; ++t) {
        const signed char* hs = &h_q[oR + (l16 & 3) * HSTR];
        i32x4 a[4];

#pragma unroll
        for (int n = 0; n < 4; ++n) {
            const int j = (j0 + n) & 3;          // chunk consumed this iteration
            // chunk j (h units 64j..64j+63) produced by waves 4j..4j+3
            while (__hip_atomic_load(&flg[4 * j + fi], __ATOMIC_ACQUIRE,
                                     __HIP_MEMORY_SCOPE_WORKGROUP) < t) { }
            const i32x4 ah = *(const i32x4*)(hs + j * 64 + lq * 16);
            if (n == 0) {
                MFMA_I8_Z(a[0], ah, wa[0][0], zz);
                MFMA_I8_Z(a[1], ah, wa[1][0], zz);
                MFMA_I8_Z(a[2], ah, wa[2][0], zz);
                MFMA_I8_Z(a[3], ah, wa[3][0], zz);
            } else if (n == 1) {
                MFMA_I8(a[0], ah, wa[0][1]); MFMA_I8(a[1], ah, wa[1][1]);
                MFMA_I8(a[2], ah, wa[2][1]); MFMA_I8(a[3], ah, wa[3][1]);
            } else if (n == 2) {
                MFMA_I8(a[0], ah, wa[0][2]); MFMA_I8(a[1], ah, wa[1][2]);
                MFMA_I8(a[2], ah, wa[2][2]); MFMA_I8(a[3], ah, wa[3][2]);
            } else {
                MFMA_I8(a[0], ah, wa[0][3]); MFMA_I8(a[1], ah, wa[1][3]);
                MFMA_I8(a[2], ah, wa[2][3]); MFMA_I8(a[3], ah, wa[3][3]);
            }
        }

        // epilogue: ONE output per lane (row=lq, unit u); acc j=lq via selects
        const float xv = x_lds[lq * XSTR + t];
        const float zs0 = __builtin_fmaf((float)EXTRACT(a[0]), SMG,
                          __builtin_fmaf(xv, wxm[0], bm[0]));
        const float zs1 = __builtin_fmaf((float)EXTRACT(a[1]), SMS,
                          __builtin_fmaf(xv, wxm[1], bm[1]));
        const float zs2 = __builtin_fmaf((float)EXTRACT(a[2]), SMS,
                          __builtin_fmaf(xv, wxm[2], bm[2]));
        const float zs3 = __builtin_fmaf((float)EXTRACT(a[3]), SMS,
                          __builtin_fmaf(xv, wxm[3], bm[3]));
        const float hh = gate_h(zs0, zs1, zs2, zs3, c);

        h_q[oW + woff] = (signed char)__float2int_rn(hh * 127.0f);
        if (t == TSTEPS - 1) proj[lq * PSTR + u] = hh;

        // publish: release orders the h ds_write before the flag store
        if (lane == 0)
            __hip_atomic_store(&flg[w], t + 1, __ATOMIC_RELEASE,
                               __HIP_MEMORY_SCOPE_WORKGROUP);

        const int tmp = oS; oS = oR; oR = oW; oW = tmp;   // rotate buffers
    }

    __syncthreads();                     // all proj writes done

    // ---- final projection: out[g*4 + r][cls], 4x10 -------------------------------
    if (tid < BB * NCLS) {
        const int r = tid / NCLS, cls = tid - r * NCLS;
        float a = b_p[cls];
#pragma unroll 8
        for (int uu = 0; uu < HDIM; ++uu)
            a = __builtin_fmaf(proj[r * PSTR + uu], w_ph[uu * NCLS + cls], a);
        out[(size_t)(g * BB + r) * NCLS + cls] = a;
    }
}

extern "C" void kernel_launch(void* const* d_in, const int* in_sizes, int n_in,
                              void* d_out, int out_size, void* d_ws, size_t ws_size,
                              hipStream_t stream)
{
    const float* x    = (const float*)d_in[0];
    const float* w_gx = (const float*)d_in[1];
    const float* w_ix = (const float*)d_in[2];
    const float* w_fx = (const float*)d_in[3];
    const float* w_ox = (const float*)d_in[4];
    const float* w_gh = (const float*)d_in[5];
    const float* w_ih = (const float*)d_in[6];
    const float* w_fh = (const float*)d_in[7];
    const float* w_oh = (const float*)d_in[8];
    const float* b_g  = (const float*)d_in[9];
    const float* b_i  = (const float*)d_in[10];
    const float* b_f  = (const float*)d_in[11];
    const float* b_o  = (const float*)d_in[12];
    const float* w_ph = (const float*)d_in[13];
    const float* b_p  = (const float*)d_in[14];

    signed char* wq8 = (signed char*)d_ws;   // 4*256*256 = 256 KB

    hipLaunchKernelGGL(pack_w, dim3(1024), dim3(64), 0, stream,
                       w_gh, w_ih, w_fh, w_oh, wq8);

    hipLaunchKernelGGL(lstm_full, dim3(NBLOCKS), dim3(NTHR), 0, stream,
                       x, w_gx, w_ix, w_fx, w_ox,
                       b_g, b_i, b_f, b_o, w_ph, b_p,
                       wq8, (float*)d_out);
}

// Round 14
// 128.074 us; speedup vs baseline: 1.0711x; 1.0032x over previous
//
#include <hip/hip_runtime.h>

// LSTM: B=1024, T=128, H=256, C=10.
// Round 14: r10 (best: 124.8us, barrier-synced, EXTRACT scheme — all validated)
// + issue-fat trims only: (1) zero-C MFMA for chunk 0 (kills 16 v_mov acc-init,
// r13-validated); (2) time loop unrolled x2 with hard-coded buffer parities and
// hoisted read bases (ds offsets fold to immediates); (3) t=127 peeled (no branch,
// no dead h-write). Compute path bit-identical to r10.
// Counter evidence r10: MfmaUtil 41% + VALUBusy 57% = 98% -> SIMD issue saturated;
// serial model 1306(MFMA)+~1250(VALU) = 2556 cyc matches measured 2560.

#define TSTEPS  128
#define HDIM    256
#define NCLS    10
#define BB      4
#define NBLOCKS 256
#define NTHR    1024

#define XSTR    132                 // floats per x row
#define HSTR    320                 // bytes per h row
#define PSTR    260

typedef char  i8x16 __attribute__((ext_vector_type(16)));
typedef int   i32x4 __attribute__((ext_vector_type(4)));

#define L2E     1.4426950408889634f
#define MGC     (-2.0f * L2E)
#define SMG     (-2.0f * L2E / 16129.0f)   // acc scale, tanh gate (1/(127*127))
#define SMS     (-1.0f * L2E / 16129.0f)   // acc scale, sigmoid gates

static __device__ __forceinline__ float rcpf(float x) { return __builtin_amdgcn_rcpf(x); }
static __device__ __forceinline__ float exp2f_fast(float x) { return __builtin_amdgcn_exp2f(x); }

#define MFMA_I8(ACC, A, B) \
    asm("v_mfma_i32_16x16x64_i8 %0, %1, %2, %0" : "+v"(ACC) : "v"(A), "a"(B))
#define MFMA_I8_Z(ACC, A, B, Z) \
    asm("v_mfma_i32_16x16x64_i8 %0, %1, %2, %3" : "=v"(ACC) : "v"(A), "a"(B), "v"(Z))

// select element j=lq from this lane's 4 acc regs (3 cndmask) — validated r10/r12/r13
#define EXTRACT(V) (s1 ? (s0 ? (V)[3] : (V)[2]) : (s0 ? (V)[1] : (V)[0]))

// gates from 4 pre-scaled logits; updates c, returns h
static __device__ __forceinline__ float gate_h(float zs0, float zs1, float zs2,
                                               float zs3, float& c)
{
    const float eg = exp2f_fast(zs0), ei = exp2f_fast(zs1);
    const float ef = exp2f_fast(zs2), eo = exp2f_fast(zs3);
    const float rg = rcpf(1.0f + eg), ri = rcpf(1.0f + ei);
    const float rf = rcpf(1.0f + ef), ro = rcpf(1.0f + eo);
    const float gg = __builtin_fmaf(2.0f, rg, -1.0f);          // tanh
    const float cc = __builtin_fmaf(c, rf, gg * ri);
    c = cc;
    const float et = exp2f_fast(cc * MGC);
    const float rt = rcpf(1.0f + et);
    const float tc = __builtin_fmaf(2.0f, rt, -1.0f);
    return tc * ro;
}

// ---------------- pre-kernel: quantize + transpose Wh to int8 [gate][unit][k] ----
__global__ __launch_bounds__(64)
void pack_w(const float* __restrict__ wg, const float* __restrict__ wi,
            const float* __restrict__ wf, const float* __restrict__ wo,
            signed char* __restrict__ wq8)
{
    const int b = blockIdx.x;            // 0..1023
    const int q = b >> 8;                // gate
    const int u = b & 255;               // unit (column)
    const float* wp = (q == 0) ? wg : (q == 1) ? wi : (q == 2) ? wf : wo;
    const int t  = threadIdx.x;          // 0..63
    const int k0 = t * 4;
    unsigned int pk = 0;
#pragma unroll
    for (int i = 0; i < 4; ++i) {
        const float v = wp[(k0 + i) * HDIM + u];
        int qv = __float2int_rn(v * 127.0f);
        qv = (qv > 127) ? 127 : ((qv < -127) ? -127 : qv);
        pk |= ((unsigned int)qv & 255u) << (8 * i);
    }
    *(unsigned int*)(wq8 + ((size_t)(q * 256 + u) * 256 + k0)) = pk;
}

// ---------------- main persistent kernel ----------------------------------------
__global__ __launch_bounds__(NTHR, 4)
void lstm_full(const float* __restrict__ x,
               const float* __restrict__ w_gx, const float* __restrict__ w_ix,
               const float* __restrict__ w_fx, const float* __restrict__ w_ox,
               const float* __restrict__ b_g,  const float* __restrict__ b_i,
               const float* __restrict__ b_f,  const float* __restrict__ b_o,
               const float* __restrict__ w_ph, const float* __restrict__ b_p,
               const signed char* __restrict__ wq8,
               float* __restrict__ out)
{
    const int g    = blockIdx.x;         // 0..255, batch rows [g*4, g*4+4)
    const int tid  = threadIdx.x;
    const int w    = tid >> 6;           // wave 0..15
    const int lane = tid & 63;
    const int l16  = lane & 15;
    const int lq   = lane >> 4;          // 0..3  == this lane's batch row

    __shared__ float        x_lds[BB * XSTR];           // 2.1 KB
    __shared__ signed char  h_q[2][BB * HSTR];          // 2.5 KB
    __shared__ float        proj[BB * PSTR];            // 4.2 KB

    {   // x tile: 4 rows x 128 steps
        const float* xs = x + (size_t)g * BB * TSTEPS;
        for (int i = tid; i < BB * TSTEPS; i += NTHR)
            x_lds[(i >> 7) * XSTR + (i & 127)] = xs[i];
    }

    // ---- int8 B-fragments, pinned in AGPRs (volatile def: no sink/remat) --------
    // wave w owns units u = w*16 + l16 (ONE unit per lane), all 4 gates.
    const int u = w * 16 + l16;
    i32x4 wa[4][4];
#pragma unroll
    for (int q = 0; q < 4; ++q)
#pragma unroll
        for (int kk = 0; kk < 4; ++kk) {
            const signed char* p = wq8 + ((size_t)(q * 256 + u) * 256)
                                       + kk * 64 + lq * 16;
            i32x4 v = __builtin_bit_cast(i32x4, *(const i8x16*)p);
            asm volatile("" : "+a"(v));
            wa[q][kk] = v;
        }

    const float* const wxp[4] = {w_gx, w_ix, w_fx, w_ox};
    const float* const bbp[4] = {b_g, b_i, b_f, b_o};
    float wxm[4], bm[4];
#pragma unroll
    for (int q = 0; q < 4; ++q) {
        const float m = (q == 0) ? MGC : (-L2E);
        wxm[q] = wxp[q][u] * m;
        bm[q]  = bbp[q][u] * m;
    }

    i32x4 zz = {0, 0, 0, 0};
    asm("" : "+v"(zz));                  // live zero C-operand (r13-validated)

    float c = 0.f;                       // cell state: lane owns (row=lq, unit u)
    const bool s0 = (lq & 1) != 0;
    const bool s1 = (lq & 2) != 0;
    const int  woff = lq * HSTR + u;     // h write offset (1 byte per lane)

    // hoisted read bases (lq*16 folded -> ds offsets become immediates)
    const signed char* hr0 = &h_q[0][(l16 & 3) * HSTR + lq * 16];
    const signed char* hr1 = &h_q[1][(l16 & 3) * HSTR + lq * 16];

    // one step: 16 MFMA (chunk0 zero-C) + epilogue; returns h for (row lq, unit u)
    auto step_h = [&](int t, const signed char* hs) -> float {
        const i32x4 ah0 = *(const i32x4*)(hs +   0);
        const i32x4 ah1 = *(const i32x4*)(hs +  64);
        const i32x4 ah2 = *(const i32x4*)(hs + 128);
        const i32x4 ah3 = *(const i32x4*)(hs + 192);

        i32x4 a0, a1, a2, a3;
        MFMA_I8_Z(a0, ah0, wa[0][0], zz);
        MFMA_I8_Z(a1, ah0, wa[1][0], zz);
        MFMA_I8_Z(a2, ah0, wa[2][0], zz);
        MFMA_I8_Z(a3, ah0, wa[3][0], zz);
        MFMA_I8(a0, ah1, wa[0][1]); MFMA_I8(a1, ah1, wa[1][1]);
        MFMA_I8(a2, ah1, wa[2][1]); MFMA_I8(a3, ah1, wa[3][1]);
        MFMA_I8(a0, ah2, wa[0][2]); MFMA_I8(a1, ah2, wa[1][2]);
        MFMA_I8(a2, ah2, wa[2][2]); MFMA_I8(a3, ah2, wa[3][2]);
        MFMA_I8(a0, ah3, wa[0][3]); MFMA_I8(a1, ah3, wa[1][3]);
        MFMA_I8(a2, ah3, wa[2][3]); MFMA_I8(a3, ah3, wa[3][3]);

        const float xv = x_lds[lq * XSTR + t];
        const float zs0 = __builtin_fmaf((float)EXTRACT(a0), SMG,
                          __builtin_fmaf(xv, wxm[0], bm[0]));
        const float zs1 = __builtin_fmaf((float)EXTRACT(a1), SMS,
                          __builtin_fmaf(xv, wxm[1], bm[1]));
        const float zs2 = __builtin_fmaf((float)EXTRACT(a2), SMS,
                          __builtin_fmaf(xv, wxm[2], bm[2]));
        const float zs3 = __builtin_fmaf((float)EXTRACT(a3), SMS,
                          __builtin_fmaf(xv, wxm[3], bm[3]));
        return gate_h(zs0, zs1, zs2, zs3, c);
    };

    __syncthreads();                     // x_lds visible

    // ---- t = 0 peel: acc = 0, z = x*Wx + b only; h(1) -> parity 1 ---------------
    {
        const float xv = x_lds[lq * XSTR + 0];
        const float hh = gate_h(__builtin_fmaf(xv, wxm[0], bm[0]),
                                __builtin_fmaf(xv, wxm[1], bm[1]),
                                __builtin_fmaf(xv, wxm[2], bm[2]),
                                __builtin_fmaf(xv, wxm[3], bm[3]), c);
        h_q[1][woff] = (signed char)__float2int_rn(hh * 127.0f);
        __syncthreads();
    }

    // ---- main loop: t = 1..126 unrolled x2 with hard-coded parities -------------
    for (int t = 1; t < TSTEPS - 1; t += 2) {
        {   // odd t: read parity 1, write parity 0
            const float hh = step_h(t, hr1);
            h_q[0][woff] = (signed char)__float2int_rn(hh * 127.0f);
            __syncthreads();
        }
        {   // even t+1: read parity 0, write parity 1
            const float hh = step_h(t + 1, hr0);
            h_q[1][woff] = (signed char)__float2int_rn(hh * 127.0f);
            __syncthreads();
        }
    }

    // ---- t = 127 peel: read parity 1, final h -> proj only ----------------------
    {
        const float hh = step_h(TSTEPS - 1, hr1);
        proj[lq * PSTR + u] = hh;
    }
    __syncthreads();

    // ---- final projection: out[g*4 + r][cls], 4x10 -------------------------------
    if (tid < BB * NCLS) {
        const int r = tid / NCLS, cls = tid - r * NCLS;
        float a = b_p[cls];
#pragma unroll 8
        for (int uu = 0; uu < HDIM; ++uu)
            a = __builtin_fmaf(proj[r * PSTR + uu], w_ph[uu * NCLS + cls], a);
        out[(size_t)(g * BB + r) * NCLS + cls] = a;
    }
}

extern "C" void kernel_launch(void* const* d_in, const int* in_sizes, int n_in,
                              void* d_out, int out_size, void* d_ws, size_t ws_size,
                              hipStream_t stream)
{
    const float* x    = (const float*)d_in[0];
    const float* w_gx = (const float*)d_in[1];
    const float* w_ix = (const float*)d_in[2];
    const float* w_fx = (const float*)d_in[3];
    const float* w_ox = (const float*)d_in[4];
    const float* w_gh = (const float*)d_in[5];
    const float* w_ih = (const float*)d_in[6];
    const float* w_fh = (const float*)d_in[7];
    const float* w_oh = (const float*)d_in[8];
    const float* b_g  = (const float*)d_in[9];
    const float* b_i  = (const float*)d_in[10];
    const float* b_f  = (const float*)d_in[11];
    const float* b_o  = (const float*)d_in[12];
    const float* w_ph = (const float*)d_in[13];
    const float* b_p  = (const float*)d_in[14];

    signed char* wq8 = (signed char*)d_ws;   // 4*256*256 = 256 KB

    hipLaunchKernelGGL(pack_w, dim3(1024), dim3(64), 0, stream,
                       w_gh, w_ih, w_fh, w_oh, wq8);

    hipLaunchKernelGGL(lstm_full, dim3(NBLOCKS), dim3(NTHR), 0, stream,
                       x, w_gx, w_ix, w_fx, w_ox,
                       b_g, b_i, b_f, b_o, w_ph, b_p,
                       wq8, (float*)d_out);
}

// Round 15
// 124.350 us; speedup vs baseline: 1.1032x; 1.0299x over previous
//
#include <hip/hip_runtime.h>

// LSTM: B=1024, T=128, H=256, C=10.
// FINAL (= round 10 verbatim, the session best: 124.8us, absmax 0.0).
// 256 blocks x 1024 thr (16 waves), BB=4 batch rows/block, 4 waves/SIMD.
// Wh int8 (q=rn(w*127)) pinned in AGPRs (volatile asm def) consumed by inline-asm
// v_mfma_i32_16x16x64_i8 with "a" B-operand -> truly register-resident weights.
// h carried as single int8 via LDS double buffer, 1 barrier/step. Each wave owns
// 16 hidden units x 4 gates; one output/lane in the epilogue (EXTRACT selects).
//
// Ceiling record: step = 2560 cyc vs 1306 cyc/SIMD MFMA B-coverage floor
// (256 KB Wh through the matrix pipe per CU per step; 64 mfma x 20.4 cyc).
// Falsified levers: source interleave (r8), setprio stagger (r9), epilogue diet
// (r11, accuracy), LDS-flag desync (r12), rotated consumption (r13), zero-C/
// unroll trims (r14). Occupancy 2->4 waves/SIMD (r10) was the last real win.

#define TSTEPS  128
#define HDIM    256
#define NCLS    10
#define BB      4
#define NBLOCKS 256
#define NTHR    1024

#define XSTR    132                 // floats per x row
#define HSTR    320                 // bytes per h row (2-way on b128 reads = free)
#define PSTR    260

typedef char  i8x16 __attribute__((ext_vector_type(16)));
typedef int   i32x4 __attribute__((ext_vector_type(4)));

#define L2E     1.4426950408889634f
#define MGC     (-2.0f * L2E)
#define SMG     (-2.0f * L2E / 16129.0f)   // acc scale, tanh gate (1/(127*127))
#define SMS     (-1.0f * L2E / 16129.0f)   // acc scale, sigmoid gates

static __device__ __forceinline__ float rcpf(float x) { return __builtin_amdgcn_rcpf(x); }
static __device__ __forceinline__ float exp2f_fast(float x) { return __builtin_amdgcn_exp2f(x); }

#define MFMA_I8(ACC, A, B) \
    asm("v_mfma_i32_16x16x64_i8 %0, %1, %2, %0" : "+v"(ACC) : "v"(A), "a"(B))

// select element j=lq from this lane's 4 acc regs (3 cndmask)
#define EXTRACT(V) (s1 ? (s0 ? (V)[3] : (V)[2]) : (s0 ? (V)[1] : (V)[0]))

// gates from 4 pre-scaled logits; updates c, returns h
static __device__ __forceinline__ float gate_h(float zs0, float zs1, float zs2,
                                               float zs3, float& c)
{
    const float eg = exp2f_fast(zs0), ei = exp2f_fast(zs1);
    const float ef = exp2f_fast(zs2), eo = exp2f_fast(zs3);
    const float rg = rcpf(1.0f + eg), ri = rcpf(1.0f + ei);
    const float rf = rcpf(1.0f + ef), ro = rcpf(1.0f + eo);
    const float gg = __builtin_fmaf(2.0f, rg, -1.0f);          // tanh
    const float cc = __builtin_fmaf(c, rf, gg * ri);
    c = cc;
    const float et = exp2f_fast(cc * MGC);
    const float rt = rcpf(1.0f + et);
    const float tc = __builtin_fmaf(2.0f, rt, -1.0f);
    return tc * ro;
}

// ---------------- pre-kernel: quantize + transpose Wh to int8 [gate][unit][k] ----
__global__ __launch_bounds__(64)
void pack_w(const float* __restrict__ wg, const float* __restrict__ wi,
            const float* __restrict__ wf, const float* __restrict__ wo,
            signed char* __restrict__ wq8)
{
    const int b = blockIdx.x;            // 0..1023
    const int q = b >> 8;                // gate
    const int u = b & 255;               // unit (column)
    const float* wp = (q == 0) ? wg : (q == 1) ? wi : (q == 2) ? wf : wo;
    const int t  = threadIdx.x;          // 0..63
    const int k0 = t * 4;
    unsigned int pk = 0;
#pragma unroll
    for (int i = 0; i < 4; ++i) {
        const float v = wp[(k0 + i) * HDIM + u];
        int qv = __float2int_rn(v * 127.0f);
        qv = (qv > 127) ? 127 : ((qv < -127) ? -127 : qv);
        pk |= ((unsigned int)qv & 255u) << (8 * i);
    }
    *(unsigned int*)(wq8 + ((size_t)(q * 256 + u) * 256 + k0)) = pk;
}

// ---------------- main persistent kernel ----------------------------------------
__global__ __launch_bounds__(NTHR, 4)
void lstm_full(const float* __restrict__ x,
               const float* __restrict__ w_gx, const float* __restrict__ w_ix,
               const float* __restrict__ w_fx, const float* __restrict__ w_ox,
               const float* __restrict__ b_g,  const float* __restrict__ b_i,
               const float* __restrict__ b_f,  const float* __restrict__ b_o,
               const float* __restrict__ w_ph, const float* __restrict__ b_p,
               const signed char* __restrict__ wq8,
               float* __restrict__ out)
{
    const int g    = blockIdx.x;         // 0..255, batch rows [g*4, g*4+4)
    const int tid  = threadIdx.x;
    const int w    = tid >> 6;           // wave 0..15
    const int lane = tid & 63;
    const int l16  = lane & 15;
    const int lq   = lane >> 4;          // 0..3  == this lane's batch row

    __shared__ float        x_lds[BB * XSTR];           // 2.1 KB
    __shared__ signed char  h_q[2][BB * HSTR];          // 2.5 KB
    __shared__ float        proj[BB * PSTR];            // 4.2 KB

    {   // x tile: 4 rows x 128 steps
        const float* xs = x + (size_t)g * BB * TSTEPS;
        for (int i = tid; i < BB * TSTEPS; i += NTHR)
            x_lds[(i >> 7) * XSTR + (i & 127)] = xs[i];
    }

    // ---- int8 B-fragments, pinned in AGPRs (volatile def: no sink/remat) --------
    // wave w owns units u = w*16 + l16 (ONE unit per lane), all 4 gates.
    // element e of lane (l16,lq), chunk kk: B[k = kk*64+lq*16+e][u]
    const int u = w * 16 + l16;
    i32x4 wa[4][4];
#pragma unroll
    for (int q = 0; q < 4; ++q)
#pragma unroll
        for (int kk = 0; kk < 4; ++kk) {
            const signed char* p = wq8 + ((size_t)(q * 256 + u) * 256)
                                       + kk * 64 + lq * 16;
            i32x4 v = __builtin_bit_cast(i32x4, *(const i8x16*)p);
            asm volatile("" : "+a"(v));
            wa[q][kk] = v;
        }

    const float* const wxp[4] = {w_gx, w_ix, w_fx, w_ox};
    const float* const bbp[4] = {b_g, b_i, b_f, b_o};
    float wxm[4], bm[4];
#pragma unroll
    for (int q = 0; q < 4; ++q) {
        const float m = (q == 0) ? MGC : (-L2E);
        wxm[q] = wxp[q][u] * m;
        bm[q]  = bbp[q][u] * m;
    }

    float c = 0.f;                       // cell state: lane owns (row=lq, unit u)
    const bool s0 = (lq & 1) != 0;
    const bool s1 = (lq & 2) != 0;
    const int  woff = lq * HSTR + u;     // h write offset (1 byte per lane)

    __syncthreads();

    // ---- t = 0 peel: acc = 0, z = x*Wx + b only ---------------------------------
    {
        const float xv = x_lds[lq * XSTR + 0];
        const float hh = gate_h(__builtin_fmaf(xv, wxm[0], bm[0]),
                                __builtin_fmaf(xv, wxm[1], bm[1]),
                                __builtin_fmaf(xv, wxm[2], bm[2]),
                                __builtin_fmaf(xv, wxm[3], bm[3]), c);
        h_q[1][woff] = (signed char)__float2int_rn(hh * 127.0f);
        __syncthreads();
    }

    // ---- main loop: t = 1 .. 127 ------------------------------------------------
    for (int t = 1; t < TSTEPS; ++t) {
        const signed char* hs = &h_q[t & 1][(l16 & 3) * HSTR];
        const i32x4 ah0 = *(const i32x4*)(hs +   0 + lq * 16);
        const i32x4 ah1 = *(const i32x4*)(hs +  64 + lq * 16);
        const i32x4 ah2 = *(const i32x4*)(hs + 128 + lq * 16);
        const i32x4 ah3 = *(const i32x4*)(hs + 192 + lq * 16);

        i32x4 a[4] = {{0,0,0,0},{0,0,0,0},{0,0,0,0},{0,0,0,0}};
#pragma unroll
        for (int q = 0; q < 4; ++q) MFMA_I8(a[q], ah0, wa[q][0]);
#pragma unroll
        for (int q = 0; q < 4; ++q) MFMA_I8(a[q], ah1, wa[q][1]);
#pragma unroll
        for (int q = 0; q < 4; ++q) MFMA_I8(a[q], ah2, wa[q][2]);
#pragma unroll
        for (int q = 0; q < 4; ++q) MFMA_I8(a[q], ah3, wa[q][3]);

        // epilogue: ONE output per lane (row=lq, unit u); acc j=lq via selects
        const float xv = x_lds[lq * XSTR + t];
        const float zs0 = __builtin_fmaf((float)EXTRACT(a[0]), SMG,
                          __builtin_fmaf(xv, wxm[0], bm[0]));
        const float zs1 = __builtin_fmaf((float)EXTRACT(a[1]), SMS,
                          __builtin_fmaf(xv, wxm[1], bm[1]));
        const float zs2 = __builtin_fmaf((float)EXTRACT(a[2]), SMS,
                          __builtin_fmaf(xv, wxm[2], bm[2]));
        const float zs3 = __builtin_fmaf((float)EXTRACT(a[3]), SMS,
                          __builtin_fmaf(xv, wxm[3], bm[3]));
        const float hh = gate_h(zs0, zs1, zs2, zs3, c);

        h_q[(t + 1) & 1][woff] = (signed char)__float2int_rn(hh * 127.0f);
        if (t == TSTEPS - 1) proj[lq * PSTR + u] = hh;
        __syncthreads();
    }

    // ---- final projection: out[g*4 + r][cls], 4x10 -------------------------------
    if (tid < BB * NCLS) {
        const int r = tid / NCLS, cls = tid - r * NCLS;
        float a = b_p[cls];
#pragma unroll 8
        for (int uu = 0; uu < HDIM; ++uu)
            a = __builtin_fmaf(proj[r * PSTR + uu], w_ph[uu * NCLS + cls], a);
        out[(size_t)(g * BB + r) * NCLS + cls] = a;
    }
}

extern "C" void kernel_launch(void* const* d_in, const int* in_sizes, int n_in,
                              void* d_out, int out_size, void* d_ws, size_t ws_size,
                              hipStream_t stream)
{
    const float* x    = (const float*)d_in[0];
    const float* w_gx = (const float*)d_in[1];
    const float* w_ix = (const float*)d_in[2];
    const float* w_fx = (const float*)d_in[3];
    const float* w_ox = (const float*)d_in[4];
    const float* w_gh = (const float*)d_in[5];
    const float* w_ih = (const float*)d_in[6];
    const float* w_fh = (const float*)d_in[7];
    const float* w_oh = (const float*)d_in[8];
    const float* b_g  = (const float*)d_in[9];
    const float* b_i  = (const float*)d_in[10];
    const float* b_f  = (const float*)d_in[11];
    const float* b_o  = (const float*)d_in[12];
    const float* w_ph = (const float*)d_in[13];
    const float* b_p  = (const float*)d_in[14];

    signed char* wq8 = (signed char*)d_ws;   // 4*256*256 = 256 KB

    hipLaunchKernelGGL(pack_w, dim3(1024), dim3(64), 0, stream,
                       w_gh, w_ih, w_fh, w_oh, wq8);

    hipLaunchKernelGGL(lstm_full, dim3(NBLOCKS), dim3(NTHR), 0, stream,
                       x, w_gx, w_ix, w_fx, w_ox,
                       b_g, b_i, b_f, b_o, w_ph, b_p,
                       wq8, (float*)d_out);
}